// Round 15
// baseline (108.522 us; speedup 1.0000x reference)
//
#include <hip/hip_runtime.h>
#include <hip/hip_bf16.h>

typedef __bf16 bf16x8 __attribute__((ext_vector_type(8)));
typedef __bf16 bf16x4 __attribute__((ext_vector_type(4)));
typedef float  f32x4  __attribute__((ext_vector_type(4)));

#define V_TOTAL 32768
#define NT      256        // 4 waves; wave owns 64 M-rows x 64 cols (acc[4][4])
#define NV      32         // v-chunks of 64 positions per block
#define NBLK    256        // 1 block/CU (160 KiB LDS); 16 blocks per sample

#define W2_LDS  131072     // [8 kt][16 mtile][4 koct][16 row] 16B chunks -> lane-LINEAR A reads
#define H1_LDS  32768      // [64 pos][32 c] chunks, c = m8 ^ (pos&7)
#define LDS_TOT (W2_LDS + H1_LDS)   // 163840 = 160 KiB exactly

// async global->LDS, 16B/lane; LDS dest = wave-uniform base + lane*16
#define GLOAD_LDS16(g, l) __builtin_amdgcn_global_load_lds( \
    (const __attribute__((address_space(1))) void*)(g),     \
    (__attribute__((address_space(3))) void*)(l), 16, 0, 0)

// ---- prep: w2 fp32 -> bf16 (RNE) into workspace ----
__global__ void w2_to_bf16(const float* __restrict__ w2, __bf16* __restrict__ w2b) {
    int i = blockIdx.x * 256 + threadIdx.x;   // grid sized exactly: 8*256*256
    w2b[i] = (__bf16)w2[i];
}

__global__ __launch_bounds__(NT) void fused_mlp(
    const float* __restrict__ x,  const int* __restrict__ obj,
    const float* __restrict__ w1, const float* __restrict__ b1,
    const float* __restrict__ b2, const float* __restrict__ w3,
    const float* __restrict__ b3, const __bf16* __restrict__ w2b,
    float* __restrict__ out)
{
    extern __shared__ __align__(16) char smem[];
    char*  w2s = smem;            // A: chunk (kt*1024 + mtile*64 + koct*16 + row) -> lane-linear
    char*  h1t = smem + W2_LDS;   // B: row pos, 16B chunk slot m8 ^ (pos&7)
    float* red = (float*)h1t;     // 1 KB alias; guarded by bar2..bar4

    const int t    = threadIdx.x;
    const int lane = t & 63;
    const int wv   = t >> 6;            // 4 waves: rows [wv*64, wv*64+64)
    const int llo  = lane & 15;
    const int lhi  = lane >> 4;
    const int b    = blockIdx.x >> 4;   // sample (16 blocks each)
    const int g    = blockIdx.x & 15;
    const int e    = __builtin_amdgcn_readfirstlane(obj[b]);
    const __bf16* w2e = w2b + (size_t)e * 65536;

    // ---- stage ALL of W2[e] into LDS once (128 KB), lane-linear frag layout ----
    #pragma unroll
    for (int it = 0; it < 32; ++it) {
        int c    = it * NT + wv * 64 + lane;      // chunk id 0..8191
        int kt   = c >> 10;
        int mt16 = (c >> 6) & 15;
        int ko   = (c >> 4) & 3;
        int row  = c & 15;
        GLOAD_LDS16(w2e + (mt16 * 16 + row) * 256 + kt * 32 + ko * 8,
                    w2s + (it * NT + wv * 64) * 16);
    }

    // ---- L1 as MFMA: W1 A-frags resident (b1/b2/w3 reloaded per chunk, L1$-hot) ----
    const float* w1e = w1 + e * 1536;
    const float* b1e = b1 + e * 256;
    const float* b2e = b2 + e * 256;
    const float* w3e = w3 + e * 256;
    bf16x8 aa1[4];
    #pragma unroll
    for (int mt2 = 0; mt2 < 4; ++mt2) {           // tile (4wv+mt2): rows +llo, k=j (lhi==0)
        const int m0 = (4 * wv + mt2) * 16;
        bf16x8 v = {};
        if (lhi == 0)
            #pragma unroll
            for (int j = 0; j < 6; ++j) v[j] = (__bf16)w1e[(m0 + llo) * 6 + j];
        aa1[mt2] = v;
    }
    const float b3e = b3[e];
    const float* xe = x + (size_t)b * 6 * V_TOTAL;

    // ---- x prefetch, pre-converted to MFMA B-frags (16 VGPRs, cvt off hot path) ----
    bf16x8 xf[4];
    #pragma unroll
    for (int pt = 0; pt < 4; ++pt) {
        bf16x8 v = {};
        #pragma unroll
        for (int i = 0; i < 6; ++i)
            v[i] = (__bf16)xe[i * V_TOTAL + g * (NV * 64) + pt * 16 + llo];
        xf[pt] = v;
    }

    for (int iv = 0; iv < NV; ++iv) {
        const int v0 = (g * NV + iv) * 64;

        // ---- layer 1 (MFMA): h1[m][pos] = relu(W1 x + b1), 4 mt x 4 pt ----
        #pragma unroll
        for (int mt2 = 0; mt2 < 4; ++mt2) {
            const f32x4 b1f = *(const f32x4*)(b1e + (4 * wv + mt2) * 16 + lhi * 4);
            const int mc0 = (4 * wv + mt2) * 2 + (lhi >> 1);  // m-octet
            #pragma unroll
            for (int pt = 0; pt < 4; ++pt) {
                f32x4 h = __builtin_amdgcn_mfma_f32_16x16x32_bf16(
                    aa1[mt2], xf[pt], b1f, 0, 0, 0);
                bf16x4 pk;
                #pragma unroll
                for (int r = 0; r < 4; ++r) pk[r] = (__bf16)fmaxf(h[r], 0.f);
                const int p = pt * 16 + llo;      // position (C col)
                *(bf16x4*)(h1t + p * 512 + ((mc0 ^ (p & 7)) << 4)
                           + (lhi & 1) * 8) = pk;
            }
        }
        if (iv + 1 < NV)   // next chunk's x: load+cvt now, latency hides under L2
            #pragma unroll
            for (int pt = 0; pt < 4; ++pt) {
                bf16x8 v = {};
                #pragma unroll
                for (int i = 0; i < 6; ++i)
                    v[i] = (__bf16)xe[i * V_TOTAL + v0 + 64 + pt * 16 + llo];
                xf[pt] = v;
            }
        __syncthreads();   // bar1: h1 ready; (iv==0: W2 staging drained too)

        // ---- layer 2: 128 MFMA/wave; A lane-linear LDS (0-conflict), B swizzled ----
        f32x4 acc[4][4];
        #pragma unroll
        for (int mt = 0; mt < 4; ++mt) {
            const f32x4 bv = *(const f32x4*)(b2e + (4 * wv + mt) * 16 + lhi * 4);
            #pragma unroll
            for (int nt = 0; nt < 4; ++nt) acc[mt][nt] = bv;
        }
        __builtin_amdgcn_s_setprio(1);
        #pragma unroll
        for (int kt = 0; kt < 8; ++kt) {
            bf16x8 bb[4];
            #pragma unroll
            for (int nt = 0; nt < 4; ++nt) {          // B[k][n], ~2-way via swizzle
                int n = nt * 16 + llo;
                bb[nt] = *(const bf16x8*)(h1t + n * 512 + (((kt * 4 + lhi) ^ (n & 7)) << 4));
            }
            #pragma unroll
            for (int mt = 0; mt < 4; ++mt) {
                const bf16x8 aw = *(const bf16x8*)(   // linear: chunk tile*64 + lane
                    w2s + kt * 16384 + ((4 * wv + mt) * 64 + lane) * 16);
                #pragma unroll
                for (int nt = 0; nt < 4; ++nt)
                    acc[mt][nt] = __builtin_amdgcn_mfma_f32_16x16x32_bf16(
                        aw, bb[nt], acc[mt][nt], 0, 0, 0);
            }
        }
        __builtin_amdgcn_s_setprio(0);

        // ---- layer 3: p[nt] = this wave's 64-row partial of w3.relu(h2) ----
        float p[4];
        #pragma unroll
        for (int nt = 0; nt < 4; ++nt) {
            float s = 0.f;
            #pragma unroll
            for (int mt = 0; mt < 4; ++mt) {
                const f32x4 wf = *(const f32x4*)(w3e + (4 * wv + mt) * 16 + lhi * 4);
                #pragma unroll
                for (int j = 0; j < 4; ++j)
                    s = fmaf(wf[j], fmaxf(acc[mt][nt][j], 0.f), s);
            }
            s += __shfl_xor(s, 16, 64);
            s += __shfl_xor(s, 32, 64);
            p[nt] = s;                                // lanes 0-15: col nt*16+lane
        }
        __syncthreads();   // bar2: all h1t reads done -> red (alias) writable
        if (lane < 16)
            #pragma unroll
            for (int nt = 0; nt < 4; ++nt)
                red[wv * 64 + nt * 16 + lane] = p[nt];
        __syncthreads();   // bar3: red ready
        if (t < 64) {
            float s = b3e;
            #pragma unroll
            for (int w4 = 0; w4 < 4; ++w4) s += red[w4 * 64 + t];
            out[(size_t)b * V_TOTAL + v0 + t] = s;
        }
        __syncthreads();   // bar4: red reads done before next L1 overwrites h1t
    }
}

extern "C" void kernel_launch(void* const* d_in, const int* in_sizes, int n_in,
                              void* d_out, int out_size, void* d_ws, size_t ws_size,
                              hipStream_t stream) {
    const float* x   = (const float*)d_in[0];
    const int*   obj = (const int*)d_in[1];
    const float* w1  = (const float*)d_in[2];
    const float* b1  = (const float*)d_in[3];
    const float* w2  = (const float*)d_in[4];
    const float* b2  = (const float*)d_in[5];
    const float* w3  = (const float*)d_in[6];
    const float* b3  = (const float*)d_in[7];
    float*  out = (float*)d_out;
    __bf16* w2b = (__bf16*)d_ws;   // 8*256*256 bf16 = 1 MB

    (void)hipFuncSetAttribute((const void*)fused_mlp,
                              hipFuncAttributeMaxDynamicSharedMemorySize, LDS_TOT);

    w2_to_bf16<<<2048, 256, 0, stream>>>(w2, w2b);
    fused_mlp<<<NBLK, NT, LDS_TOT, stream>>>(x, obj, w1, b1, b2, w3, b3, w2b, out);
}

// Round 16
// 89.547 us; speedup vs baseline: 1.2119x; 1.2119x over previous
//
#include <hip/hip_runtime.h>
#include <hip/hip_bf16.h>

typedef __bf16 bf16x8 __attribute__((ext_vector_type(8)));
typedef __bf16 bf16x4 __attribute__((ext_vector_type(4)));
typedef float  f32x4  __attribute__((ext_vector_type(4)));

#define V_TOTAL 32768
#define NT      512        // 8 waves (2/SIMD — R15 showed 1/SIMD is latency-death)
#define NV      32         // v-chunks of 64 positions per block
#define NBLK    256        // 1 block/CU (160 KiB LDS); 16 blocks per sample

#define W2_LDS  131072     // [8 kt][16 mtile][4 koct][16 row] 16B chunks -> lane-LINEAR A reads
#define H1_LDS  32768      // [8 kt][4 nt][64 lane] 16B chunks -> lane-LINEAR B reads
#define LDS_TOT (W2_LDS + H1_LDS)   // 163840 = 160 KiB exactly

// async global->LDS, 16B/lane; LDS dest = wave-uniform base + lane*16
#define GLOAD_LDS16(g, l) __builtin_amdgcn_global_load_lds( \
    (const __attribute__((address_space(1))) void*)(g),     \
    (__attribute__((address_space(3))) void*)(l), 16, 0, 0)

// ---- prep: w2 fp32 -> bf16 (RNE) into workspace ----
__global__ void w2_to_bf16(const float* __restrict__ w2, __bf16* __restrict__ w2b) {
    int i = blockIdx.x * 256 + threadIdx.x;   // grid sized exactly: 8*256*256
    w2b[i] = (__bf16)w2[i];
}

__global__ __launch_bounds__(NT) void fused_mlp(
    const float* __restrict__ x,  const int* __restrict__ obj,
    const float* __restrict__ w1, const float* __restrict__ b1,
    const float* __restrict__ b2, const float* __restrict__ w3,
    const float* __restrict__ b3, const __bf16* __restrict__ w2b,
    float* __restrict__ out)
{
    extern __shared__ __align__(16) char smem[];
    char*  w2s = smem;            // A: chunk (kt*1024 + mtile*64 + koct*16 + row) -> lane-linear
    char*  h1t = smem + W2_LDS;   // B: chunk (kt*256 + nt*64 + lane): h1[m-octet][col]
    float* red = (float*)h1t;     // 2 KB alias; guarded by bar2..bar4

    const int t    = threadIdx.x;
    const int lane = t & 63;
    const int wv   = t >> 6;            // wave owns rows [(2wv)*16, (2wv+2)*16)
    const int llo  = lane & 15;
    const int lhi  = lane >> 4;
    const int b    = blockIdx.x >> 4;   // sample (16 blocks each)
    const int g    = blockIdx.x & 15;
    const int e    = __builtin_amdgcn_readfirstlane(obj[b]);
    const __bf16* w2e = w2b + (size_t)e * 65536;

    // ---- stage ALL of W2[e] into LDS once (128 KB), lane-linear frag layout ----
    #pragma unroll
    for (int it = 0; it < 16; ++it) {
        int c    = it * NT + wv * 64 + lane;      // chunk id 0..8191
        int kt   = c >> 10;
        int mt16 = (c >> 6) & 15;
        int ko   = (c >> 4) & 3;
        int row  = c & 15;
        GLOAD_LDS16(w2e + (mt16 * 16 + row) * 256 + kt * 32 + ko * 8,
                    w2s + (it * NT + wv * 64) * 16);
    }

    // ---- L1 as MFMA: W1 A-frags + hoisted bias/weight frags, all resident ----
    const float* w1e = w1 + e * 1536;
    bf16x8 aa1[2];
    f32x4  b1f[2], bv[2], wf[2];
    #pragma unroll
    for (int mt2 = 0; mt2 < 2; ++mt2) {
        const int m0 = (2 * wv + mt2) * 16;
        bf16x8 v = {};
        if (lhi == 0)
            #pragma unroll
            for (int j = 0; j < 6; ++j) v[j] = (__bf16)w1e[(m0 + llo) * 6 + j];
        aa1[mt2] = v;
        b1f[mt2] = *(const f32x4*)(b1 + e * 256 + m0 + lhi * 4);
        bv[mt2]  = *(const f32x4*)(b2 + e * 256 + m0 + lhi * 4);
        wf[mt2]  = *(const f32x4*)(w3 + e * 256 + m0 + lhi * 4);
    }
    const float b3e = b3[e];
    const float* xe = x + (size_t)b * 6 * V_TOTAL;

    // ---- x prefetch, pre-converted to MFMA B-frags (16 VGPRs) ----
    bf16x8 xf[4];
    #pragma unroll
    for (int pt = 0; pt < 4; ++pt) {
        bf16x8 v = {};
        #pragma unroll
        for (int i = 0; i < 6; ++i)
            v[i] = (__bf16)xe[i * V_TOTAL + g * (NV * 64) + pt * 16 + llo];
        xf[pt] = v;
    }

    for (int iv = 0; iv < NV; ++iv) {
        const int v0 = (g * NV + iv) * 64;

        // ---- layer 1 (MFMA): h1[m][pos] = relu(W1 x + b1), 2 mt x 4 pt ----
        #pragma unroll
        for (int mt2 = 0; mt2 < 2; ++mt2) {
            const int o = (2 * wv + mt2) * 2 + (lhi >> 1);   // m-octet 0..31
            // frag-linear dest: chunk (o>>2)*256 + pt*64 + (o&3)*16 + llo
            char* wbase = h1t + (o >> 2) * 4096 + (o & 3) * 256
                              + llo * 16 + (lhi & 1) * 8;
            #pragma unroll
            for (int pt = 0; pt < 4; ++pt) {
                f32x4 h = __builtin_amdgcn_mfma_f32_16x16x32_bf16(
                    aa1[mt2], xf[pt], b1f[mt2], 0, 0, 0);
                bf16x4 pk;
                #pragma unroll
                for (int r = 0; r < 4; ++r) pk[r] = (__bf16)fmaxf(h[r], 0.f);
                *(bf16x4*)(wbase + pt * 1024) = pk;
            }
        }
        if (iv + 1 < NV)   // next chunk's x: load+cvt now, latency hides under L2
            #pragma unroll
            for (int pt = 0; pt < 4; ++pt) {
                bf16x8 v = {};
                #pragma unroll
                for (int i = 0; i < 6; ++i)
                    v[i] = (__bf16)xe[i * V_TOTAL + v0 + 64 + pt * 16 + llo];
                xf[pt] = v;
            }
        __syncthreads();   // bar1: h1 ready; (iv==0: W2 staging drained too)

        // ---- layer 2: 64 MFMA/wave; A AND B lane-linear (0-conflict, imm offsets) ----
        f32x4 acc[2][4];
        #pragma unroll
        for (int mt = 0; mt < 2; ++mt)
            #pragma unroll
            for (int nt = 0; nt < 4; ++nt) acc[mt][nt] = bv[mt];
        const char* abase = w2s + wv * 2048 + lane * 16;   // + kt*16384 + mt*1024
        const char* bbase = h1t + lane * 16;               // + kt*4096  + nt*1024
        __builtin_amdgcn_s_setprio(1);
        #pragma unroll
        for (int kt = 0; kt < 8; ++kt) {
            bf16x8 bb[4];
            #pragma unroll
            for (int nt = 0; nt < 4; ++nt)
                bb[nt] = *(const bf16x8*)(bbase + kt * 4096 + nt * 1024);
            #pragma unroll
            for (int mt = 0; mt < 2; ++mt) {
                const bf16x8 aw = *(const bf16x8*)(abase + kt * 16384 + mt * 1024);
                #pragma unroll
                for (int nt = 0; nt < 4; ++nt)
                    acc[mt][nt] = __builtin_amdgcn_mfma_f32_16x16x32_bf16(
                        aw, bb[nt], acc[mt][nt], 0, 0, 0);
            }
        }
        __builtin_amdgcn_s_setprio(0);

        // ---- layer 3: p[nt] = this wave's 32-row partial of w3.relu(h2) ----
        float p[4];
        #pragma unroll
        for (int nt = 0; nt < 4; ++nt) {
            float s = 0.f;
            #pragma unroll
            for (int mt = 0; mt < 2; ++mt)
                #pragma unroll
                for (int j = 0; j < 4; ++j)
                    s = fmaf(wf[mt][j], fmaxf(acc[mt][nt][j], 0.f), s);
            s += __shfl_xor(s, 16, 64);
            s += __shfl_xor(s, 32, 64);
            p[nt] = s;                                // lanes 0-15: col nt*16+lane
        }
        __syncthreads();   // bar2: all h1t reads done -> red (alias) writable
        if (lane < 16)
            #pragma unroll
            for (int nt = 0; nt < 4; ++nt)
                red[wv * 64 + nt * 16 + lane] = p[nt];
        __syncthreads();   // bar3: red ready
        if (t < 64) {
            float s = b3e;
            #pragma unroll
            for (int w8 = 0; w8 < 8; ++w8) s += red[w8 * 64 + t];
            out[(size_t)b * V_TOTAL + v0 + t] = s;
        }
        __syncthreads();   // bar4: red reads done before next L1 overwrites h1t
    }
}

extern "C" void kernel_launch(void* const* d_in, const int* in_sizes, int n_in,
                              void* d_out, int out_size, void* d_ws, size_t ws_size,
                              hipStream_t stream) {
    const float* x   = (const float*)d_in[0];
    const int*   obj = (const int*)d_in[1];
    const float* w1  = (const float*)d_in[2];
    const float* b1  = (const float*)d_in[3];
    const float* w2  = (const float*)d_in[4];
    const float* b2  = (const float*)d_in[5];
    const float* w3  = (const float*)d_in[6];
    const float* b3  = (const float*)d_in[7];
    float*  out = (float*)d_out;
    __bf16* w2b = (__bf16*)d_ws;   // 8*256*256 bf16 = 1 MB

    (void)hipFuncSetAttribute((const void*)fused_mlp,
                              hipFuncAttributeMaxDynamicSharedMemorySize, LDS_TOT);

    w2_to_bf16<<<2048, 256, 0, stream>>>(w2, w2b);
    fused_mlp<<<NBLK, NT, LDS_TOT, stream>>>(x, obj, w1, b1, b2, w3, b3, w2b, out);
}

// Round 22
// 84.157 us; speedup vs baseline: 1.2895x; 1.0640x over previous
//
#include <hip/hip_runtime.h>
#include <hip/hip_bf16.h>

typedef __bf16 bf16x8 __attribute__((ext_vector_type(8)));
typedef __bf16 bf16x4 __attribute__((ext_vector_type(4)));
typedef float  f32x4  __attribute__((ext_vector_type(4)));

#define V_TOTAL 32768
#define NT      512        // 8 waves (2/SIMD; R15 showed 1/SIMD is latency-death)
#define NV      32         // v-chunks of 64 positions per block
#define NBLK    256        // 1 block/CU; 16 blocks per sample

#define W2_LDS  114688     // 7 of 8 kt panels (kt=7 lives in registers)
#define H1_LDS  32768      // [8 kt][4 nt][64 lane] 16B chunks -> lane-LINEAR B reads
#define RED_LDS 4096       // red[2][512]: 8 waves x 64 per parity (R17 bug: was 256/parity)
#define LDS_TOT (W2_LDS + H1_LDS + RED_LDS)   // 151552 < 160 KiB

// async global->LDS, 16B/lane; LDS dest = wave-uniform base (+lane*16 by HW)
#define GLOAD_LDS16(g, l) __builtin_amdgcn_global_load_lds( \
    (const __attribute__((address_space(1))) void*)(g),     \
    (__attribute__((address_space(3))) void*)(l), 16, 0, 0)

// ---- prep: w2 fp32 -> bf16 in LDS-chunk order ----
// dst index i: e = i>>16; c = (i&65535)>>3 (16B chunk); j = i&7
// chunk c = kt*1024 + mt16*64 + ko*16 + row  ->  m = mt16*16+row, k = kt*32+ko*8+j
__global__ void w2_to_bf16(const float* __restrict__ w2, __bf16* __restrict__ w2b) {
    int i = blockIdx.x * 256 + threadIdx.x;   // 8*256*256 total
    int e = i >> 16, q = i & 65535, c = q >> 3, j = q & 7;
    int kt = c >> 10, mt16 = (c >> 6) & 15, ko = (c >> 4) & 3, row = c & 15;
    w2b[i] = (__bf16)w2[e * 65536 + (mt16 * 16 + row) * 256 + kt * 32 + ko * 8 + j];
}

__global__ __launch_bounds__(NT) void fused_mlp(
    const float* __restrict__ x,  const int* __restrict__ obj,
    const float* __restrict__ w1, const float* __restrict__ b1,
    const float* __restrict__ b2, const float* __restrict__ w3,
    const float* __restrict__ b3, const __bf16* __restrict__ w2b,
    float* __restrict__ out)
{
    extern __shared__ __align__(16) char smem[];
    char*  w2s = smem;                      // kt 0..6: chunk (kt*1024+mtile*64+koct*16+row)
    char*  h1t = smem + W2_LDS;             // chunk (kt*256 + nt*64 + lane)
    float* red = (float*)(smem + W2_LDS + H1_LDS);   // [2][512] ping-pong

    const int t    = threadIdx.x;
    const int lane = t & 63;
    const int wv   = t >> 6;                // wave owns rows [wv*32, wv*32+32)
    const int llo  = lane & 15;
    const int lhi  = lane >> 4;
    const int b    = blockIdx.x >> 4;       // sample (16 blocks each)
    const int g    = blockIdx.x & 15;
    const int e    = __builtin_amdgcn_readfirstlane(obj[b]);
    const __bf16* w2sw = w2b + (size_t)e * 65536;   // pre-swizzled chunk order

    // ---- stage kt 0..6 of W2[e] (112 KB): fully coalesced 1KB/wave loads ----
    #pragma unroll
    for (int it = 0; it < 14; ++it) {
        int c0 = it * NT + wv * 64;         // wave-uniform chunk base (lane adds 16B)
        GLOAD_LDS16(w2sw + c0 * 8 + lane * 8, w2s + c0 * 16);
    }

    // ---- kt=7 A-frags in registers (frees 16 KB LDS for red) ----
    bf16x8 aa7[2];
    #pragma unroll
    for (int mt = 0; mt < 2; ++mt) {        // chunk 7168 + tile*64 + lane
        int c = 7168 + (2 * wv + mt) * 64 + lane;
        aa7[mt] = *(const bf16x8*)(w2sw + c * 8);
    }

    // ---- L1 as MFMA: W1 A-frags + hoisted bias/weight frags, all resident ----
    const float* w1e = w1 + e * 1536;
    bf16x8 aa1[2];
    f32x4  b1f[2], bv[2], wf[2];
    #pragma unroll
    for (int mt2 = 0; mt2 < 2; ++mt2) {
        const int m0 = (2 * wv + mt2) * 16;
        bf16x8 v = {};
        if (lhi == 0)
            #pragma unroll
            for (int j = 0; j < 6; ++j) v[j] = (__bf16)w1e[(m0 + llo) * 6 + j];
        aa1[mt2] = v;
        b1f[mt2] = *(const f32x4*)(b1 + e * 256 + m0 + lhi * 4);
        bv[mt2]  = *(const f32x4*)(b2 + e * 256 + m0 + lhi * 4);
        wf[mt2]  = *(const f32x4*)(w3 + e * 256 + m0 + lhi * 4);
    }
    const float b3e = b3[e];
    const float* xe = x + (size_t)b * 6 * V_TOTAL;

    // ---- x prefetch, pre-converted to MFMA B-frags (16 VGPRs) ----
    bf16x8 xf[4];
    #pragma unroll
    for (int pt = 0; pt < 4; ++pt) {
        bf16x8 v = {};
        #pragma unroll
        for (int i = 0; i < 6; ++i)
            v[i] = (__bf16)xe[i * V_TOTAL + g * (NV * 64) + pt * 16 + llo];
        xf[pt] = v;
    }

    for (int iv = 0; iv < NV; ++iv) {
        const int v0 = (g * NV + iv) * 64;

        // ---- layer 1 (MFMA): h1[m][pos] = relu(W1 x + b1), 2 mt x 4 pt ----
        #pragma unroll
        for (int mt2 = 0; mt2 < 2; ++mt2) {
            const int o = (2 * wv + mt2) * 2 + (lhi >> 1);   // m-octet 0..31
            char* wbase = h1t + (o >> 2) * 4096 + (o & 3) * 256
                              + llo * 16 + (lhi & 1) * 8;
            #pragma unroll
            for (int pt = 0; pt < 4; ++pt) {
                f32x4 h = __builtin_amdgcn_mfma_f32_16x16x32_bf16(
                    aa1[mt2], xf[pt], b1f[mt2], 0, 0, 0);
                bf16x4 pk;
                #pragma unroll
                for (int r = 0; r < 4; ++r) pk[r] = (__bf16)fmaxf(h[r], 0.f);
                *(bf16x4*)(wbase + pt * 1024) = pk;
            }
        }
        if (iv + 1 < NV)   // next chunk's x: load+cvt now, latency hides under L2
            #pragma unroll
            for (int pt = 0; pt < 4; ++pt) {
                bf16x8 v = {};
                #pragma unroll
                for (int i = 0; i < 6; ++i)
                    v[i] = (__bf16)xe[i * V_TOTAL + v0 + 64 + pt * 16 + llo];
                xf[pt] = v;
            }
        __syncthreads();   // bar1: h1 ready (iv==0: W2 staging drained too)

        // ---- layer 2: 64 MFMA/wave; A/B lane-linear; kt7 A from registers ----
        f32x4 acc[2][4];
        #pragma unroll
        for (int mt = 0; mt < 2; ++mt)
            #pragma unroll
            for (int nt = 0; nt < 4; ++nt) acc[mt][nt] = bv[mt];
        const char* abase = w2s + wv * 2048 + lane * 16;   // + kt*16384 + mt*1024
        const char* bbase = h1t + lane * 16;               // + kt*4096  + nt*1024
        __builtin_amdgcn_s_setprio(1);
        #pragma unroll
        for (int kt = 0; kt < 7; ++kt) {
            bf16x8 bb[4];
            #pragma unroll
            for (int nt = 0; nt < 4; ++nt)
                bb[nt] = *(const bf16x8*)(bbase + kt * 4096 + nt * 1024);
            #pragma unroll
            for (int mt = 0; mt < 2; ++mt) {
                const bf16x8 aw = *(const bf16x8*)(abase + kt * 16384 + mt * 1024);
                #pragma unroll
                for (int nt = 0; nt < 4; ++nt)
                    acc[mt][nt] = __builtin_amdgcn_mfma_f32_16x16x32_bf16(
                        aw, bb[nt], acc[mt][nt], 0, 0, 0);
            }
        }
        {   // kt = 7: A from registers
            bf16x8 bb[4];
            #pragma unroll
            for (int nt = 0; nt < 4; ++nt)
                bb[nt] = *(const bf16x8*)(bbase + 7 * 4096 + nt * 1024);
            #pragma unroll
            for (int mt = 0; mt < 2; ++mt)
                #pragma unroll
                for (int nt = 0; nt < 4; ++nt)
                    acc[mt][nt] = __builtin_amdgcn_mfma_f32_16x16x32_bf16(
                        aa7[mt], bb[nt], acc[mt][nt], 0, 0, 0);
        }
        __builtin_amdgcn_s_setprio(0);

        // ---- layer 3: p[nt] = this wave's 32-row partial of w3.relu(h2) ----
        float p[4];
        #pragma unroll
        for (int nt = 0; nt < 4; ++nt) {
            float s = 0.f;
            #pragma unroll
            for (int mt = 0; mt < 2; ++mt)
                #pragma unroll
                for (int j = 0; j < 4; ++j)
                    s = fmaf(wf[mt][j], fmaxf(acc[mt][nt][j], 0.f), s);
            s += __shfl_xor(s, 16, 64);
            s += __shfl_xor(s, 32, 64);
            p[nt] = s;                                // lanes 0-15: col nt*16+lane
        }
        // red ping-pong: parity buffer is 512 floats (8 waves x 64). Reads of this
        // parity finished before bar1 of the previous chunk -> no pre-write barrier.
        float* rp = red + (iv & 1) * 512;
        if (lane < 16)
            #pragma unroll
            for (int nt = 0; nt < 4; ++nt)
                rp[wv * 64 + nt * 16 + lane] = p[nt];
        __syncthreads();   // bar2: red ready; also fences h1t reads (L2 phase done
                           // by all waves) before next chunk's L1 overwrites h1t
        if (t < 64) {
            float s = b3e;
            #pragma unroll
            for (int w8 = 0; w8 < 8; ++w8) s += rp[w8 * 64 + t];
            out[(size_t)b * V_TOTAL + v0 + t] = s;
        }
        // rp reads complete before this thread's bar1 of next chunk; same-parity
        // rewrite is 2 chunks (3 barriers) away -> safe
    }
}

extern "C" void kernel_launch(void* const* d_in, const int* in_sizes, int n_in,
                              void* d_out, int out_size, void* d_ws, size_t ws_size,
                              hipStream_t stream) {
    const float* x   = (const float*)d_in[0];
    const int*   obj = (const int*)d_in[1];
    const float* w1  = (const float*)d_in[2];
    const float* b1  = (const float*)d_in[3];
    const float* w2  = (const float*)d_in[4];
    const float* b2  = (const float*)d_in[5];
    const float* w3  = (const float*)d_in[6];
    const float* b3  = (const float*)d_in[7];
    float*  out = (float*)d_out;
    __bf16* w2b = (__bf16*)d_ws;   // 8*256*256 bf16 = 1 MB, LDS-chunk order

    (void)hipFuncSetAttribute((const void*)fused_mlp,
                              hipFuncAttributeMaxDynamicSharedMemorySize, LDS_TOT);

    w2_to_bf16<<<2048, 256, 0, stream>>>(w2, w2b);
    fused_mlp<<<NBLK, NT, LDS_TOT, stream>>>(x, obj, w1, b1, b2, w3, b3, w2b, out);
}

// Round 23
// 81.685 us; speedup vs baseline: 1.3285x; 1.0303x over previous
//
#include <hip/hip_runtime.h>
#include <hip/hip_bf16.h>

typedef __bf16 bf16x8 __attribute__((ext_vector_type(8)));
typedef __bf16 bf16x4 __attribute__((ext_vector_type(4)));
typedef float  f32x4  __attribute__((ext_vector_type(4)));

#define V_TOTAL 32768
#define NT      512        // 8 waves (2/SIMD)
#define NV      32         // v-chunks of 64 positions per block
#define NBLK    256        // 1 block/CU; 16 blocks per sample

#define NKLDS   5                      // kt panels 0..4 in LDS; 5..7 in registers
#define W2_LDS  (NKLDS * 16384)        // 81920
#define H1_LDS  65536                  // h1[2] double buffer: 2 x 32 KB
#define RED_LDS 4096                   // red[2][512]
#define LDS_TOT (W2_LDS + H1_LDS + RED_LDS)   // 151552 < 160 KiB

// async global->LDS, 16B/lane; LDS dest = wave-uniform base (+lane*16 by HW)
#define GLOAD_LDS16(g, l) __builtin_amdgcn_global_load_lds( \
    (const __attribute__((address_space(1))) void*)(g),     \
    (__attribute__((address_space(3))) void*)(l), 16, 0, 0)

// ---- prep: w2 fp32 -> bf16 in LDS-chunk order ----
// chunk c = kt*1024 + mt16*64 + ko*16 + row  ->  m = mt16*16+row, k = kt*32+ko*8+j
__global__ void w2_to_bf16(const float* __restrict__ w2, __bf16* __restrict__ w2b) {
    int i = blockIdx.x * 256 + threadIdx.x;   // 8*256*256 total
    int e = i >> 16, q = i & 65535, c = q >> 3, j = q & 7;
    int kt = c >> 10, mt16 = (c >> 6) & 15, ko = (c >> 4) & 3, row = c & 15;
    w2b[i] = (__bf16)w2[e * 65536 + (mt16 * 16 + row) * 256 + kt * 32 + ko * 8 + j];
}

__global__ __launch_bounds__(NT) void fused_mlp(
    const float* __restrict__ x,  const int* __restrict__ obj,
    const float* __restrict__ w1, const float* __restrict__ b1,
    const float* __restrict__ b2, const float* __restrict__ w3,
    const float* __restrict__ b3, const __bf16* __restrict__ w2b,
    float* __restrict__ out)
{
    extern __shared__ __align__(16) char smem[];
    char*  w2s = smem;                      // kt 0..4, chunk (kt*1024+mtile*64+koct*16+row)
    char*  h1t = smem + W2_LDS;             // [2 panels][kt*256 + nt*64 + lane]
    float* red = (float*)(smem + W2_LDS + H1_LDS);   // [2][512] ping-pong

    const int t    = threadIdx.x;
    const int lane = t & 63;
    const int wv   = t >> 6;                // wave owns rows [wv*32, wv*32+32)
    const int llo  = lane & 15;
    const int lhi  = lane >> 4;
    const int b    = blockIdx.x >> 4;       // sample (16 blocks each)
    const int g    = blockIdx.x & 15;
    const int e    = __builtin_amdgcn_readfirstlane(obj[b]);
    const __bf16* w2sw = w2b + (size_t)e * 65536;   // pre-swizzled chunk order

    // ---- stage kt 0..4 of W2[e] (80 KB): coalesced 1KB/wave loads ----
    #pragma unroll
    for (int it = 0; it < 10; ++it) {
        int c0 = it * NT + wv * 64;         // wave-uniform chunk base
        GLOAD_LDS16(w2sw + c0 * 8 + lane * 8, w2s + c0 * 16);
    }

    // ---- kt 5..7 A-frags in registers (frees 48 KB LDS for h1 dbuf) ----
    bf16x8 aar[3][2];
    #pragma unroll
    for (int k2 = 0; k2 < 3; ++k2)
        #pragma unroll
        for (int mt = 0; mt < 2; ++mt) {
            int c = (5 + k2) * 1024 + (2 * wv + mt) * 64 + lane;
            aar[k2][mt] = *(const bf16x8*)(w2sw + c * 8);
        }

    // ---- L1 as MFMA: W1 A-frags + hoisted bias/weight frags, resident ----
    const float* w1e = w1 + e * 1536;
    bf16x8 aa1[2];
    f32x4  b1f[2], bv[2], wf[2];
    #pragma unroll
    for (int mt2 = 0; mt2 < 2; ++mt2) {
        const int m0 = (2 * wv + mt2) * 16;
        bf16x8 v = {};
        if (lhi == 0)
            #pragma unroll
            for (int j = 0; j < 6; ++j) v[j] = (__bf16)w1e[(m0 + llo) * 6 + j];
        aa1[mt2] = v;
        b1f[mt2] = *(const f32x4*)(b1 + e * 256 + m0 + lhi * 4);
        bv[mt2]  = *(const f32x4*)(b2 + e * 256 + m0 + lhi * 4);
        wf[mt2]  = *(const f32x4*)(w3 + e * 256 + m0 + lhi * 4);
    }
    const float b3e = b3[e];
    const float* xe = x + (size_t)b * 6 * V_TOTAL;

    bf16x8 xf[4];
    auto load_x = [&](int ic) {             // xf <- x(chunk ic), pre-cvt bf16
        #pragma unroll
        for (int pt = 0; pt < 4; ++pt) {
            bf16x8 v = {};
            #pragma unroll
            for (int i = 0; i < 6; ++i)
                v[i] = (__bf16)xe[i * V_TOTAL + (g * NV + ic) * 64 + pt * 16 + llo];
            xf[pt] = v;
        }
    };
    auto do_l1 = [&](int pan) {             // h1(panel) = relu(W1 x + b1), MFMA
        #pragma unroll
        for (int mt2 = 0; mt2 < 2; ++mt2) {
            const int o = (2 * wv + mt2) * 2 + (lhi >> 1);   // m-octet 0..31
            char* wbase = h1t + pan * 32768 + (o >> 2) * 4096 + (o & 3) * 256
                              + llo * 16 + (lhi & 1) * 8;
            #pragma unroll
            for (int pt = 0; pt < 4; ++pt) {
                f32x4 h = __builtin_amdgcn_mfma_f32_16x16x32_bf16(
                    aa1[mt2], xf[pt], b1f[mt2], 0, 0, 0);
                bf16x4 pk;
                #pragma unroll
                for (int r = 0; r < 4; ++r) pk[r] = (__bf16)fmaxf(h[r], 0.f);
                *(bf16x4*)(wbase + pt * 1024) = pk;
            }
        }
    };

    // ---- prologue: L1(0) into panel 0; prefetch x(1) ----
    load_x(0);
    do_l1(0);
    load_x(1);

    for (int iv = 0; iv < NV; ++iv) {
        __syncthreads();   // panel iv&1 ready; red[(iv-1)&1] ready; (iv==0: staging drained)

        if (iv > 0 && t < 64) {             // out-write for chunk iv-1
            const float* rq = red + ((iv - 1) & 1) * 512;
            float s = b3e;
            #pragma unroll
            for (int w8 = 0; w8 < 8; ++w8) s += rq[w8 * 64 + t];
            out[(size_t)b * V_TOTAL + (g * NV + iv - 1) * 64 + t] = s;
        }

        // ---- layer 2: kt 0..4 A from LDS, kt 5..7 A from registers ----
        f32x4 acc[2][4];
        #pragma unroll
        for (int mt = 0; mt < 2; ++mt)
            #pragma unroll
            for (int nt = 0; nt < 4; ++nt) acc[mt][nt] = bv[mt];
        const char* abase = w2s + wv * 2048 + lane * 16;
        const char* bbase = h1t + (iv & 1) * 32768 + lane * 16;
        __builtin_amdgcn_s_setprio(1);
        #pragma unroll
        for (int kt = 0; kt < 5; ++kt) {
            bf16x8 bb[4];
            #pragma unroll
            for (int nt = 0; nt < 4; ++nt)
                bb[nt] = *(const bf16x8*)(bbase + kt * 4096 + nt * 1024);
            #pragma unroll
            for (int mt = 0; mt < 2; ++mt) {
                const bf16x8 aw = *(const bf16x8*)(abase + kt * 16384 + mt * 1024);
                #pragma unroll
                for (int nt = 0; nt < 4; ++nt)
                    acc[mt][nt] = __builtin_amdgcn_mfma_f32_16x16x32_bf16(
                        aw, bb[nt], acc[mt][nt], 0, 0, 0);
            }
        }
        #pragma unroll
        for (int k2 = 0; k2 < 3; ++k2) {
            bf16x8 bb[4];
            #pragma unroll
            for (int nt = 0; nt < 4; ++nt)
                bb[nt] = *(const bf16x8*)(bbase + (5 + k2) * 4096 + nt * 1024);
            #pragma unroll
            for (int mt = 0; mt < 2; ++mt)
                #pragma unroll
                for (int nt = 0; nt < 4; ++nt)
                    acc[mt][nt] = __builtin_amdgcn_mfma_f32_16x16x32_bf16(
                        aar[k2][mt], bb[nt], acc[mt][nt], 0, 0, 0);
        }
        __builtin_amdgcn_s_setprio(0);

        // ---- layer 3 partials into red[iv&1] ----
        float p[4];
        #pragma unroll
        for (int nt = 0; nt < 4; ++nt) {
            float s = 0.f;
            #pragma unroll
            for (int mt = 0; mt < 2; ++mt)
                #pragma unroll
                for (int j = 0; j < 4; ++j)
                    s = fmaf(wf[mt][j], fmaxf(acc[mt][nt][j], 0.f), s);
            s += __shfl_xor(s, 16, 64);
            s += __shfl_xor(s, 32, 64);
            p[nt] = s;
        }
        float* rp = red + (iv & 1) * 512;
        if (lane < 16)
            #pragma unroll
            for (int nt = 0; nt < 4; ++nt)
                rp[wv * 64 + nt * 16 + lane] = p[nt];

        // ---- L1(iv+1) into panel (iv+1)&1 (overlaps other waves' L2) ----
        if (iv + 1 < NV) {
            do_l1((iv + 1) & 1);
            if (iv + 2 < NV) load_x(iv + 2);
        }
    }
    __syncthreads();   // red[(NV-1)&1] ready
    if (t < 64) {
        const float* rq = red + ((NV - 1) & 1) * 512;
        float s = b3e;
        #pragma unroll
        for (int w8 = 0; w8 < 8; ++w8) s += rq[w8 * 64 + t];
        out[(size_t)b * V_TOTAL + (g * NV + NV - 1) * 64 + t] = s;
    }
}

extern "C" void kernel_launch(void* const* d_in, const int* in_sizes, int n_in,
                              void* d_out, int out_size, void* d_ws, size_t ws_size,
                              hipStream_t stream) {
    const float* x   = (const float*)d_in[0];
    const int*   obj = (const int*)d_in[1];
    const float* w1  = (const float*)d_in[2];
    const float* b1  = (const float*)d_in[3];
    const float* w2  = (const float*)d_in[4];
    const float* b2  = (const float*)d_in[5];
    const float* w3  = (const float*)d_in[6];
    const float* b3  = (const float*)d_in[7];
    float*  out = (float*)d_out;
    __bf16* w2b = (__bf16*)d_ws;   // 8*256*256 bf16 = 1 MB, LDS-chunk order

    (void)hipFuncSetAttribute((const void*)fused_mlp,
                              hipFuncAttributeMaxDynamicSharedMemorySize, LDS_TOT);

    w2_to_bf16<<<2048, 256, 0, stream>>>(w2, w2b);
    fused_mlp<<<NBLK, NT, LDS_TOT, stream>>>(x, obj, w1, b1, b2, w3, b3, w2b, out);
}

// Round 24
// 81.404 us; speedup vs baseline: 1.3331x; 1.0035x over previous
//
#include <hip/hip_runtime.h>
#include <hip/hip_bf16.h>

typedef __bf16 bf16x8 __attribute__((ext_vector_type(8)));
typedef __bf16 bf16x4 __attribute__((ext_vector_type(4)));
typedef float  f32x4  __attribute__((ext_vector_type(4)));

#define V_TOTAL 32768
#define NT      512        // 8 waves (2/SIMD)
#define NV      32         // v-chunks of 64 positions per block
#define NBLK    256        // 1 block/CU; 16 blocks per sample

#define NKLDS   2                      // kt panels 0..1 in LDS; 2..7 in registers
#define W2_LDS  (NKLDS * 16384)        // 32768
#define H1_LDS  65536                  // h1[2] double buffer: 2 x 32 KB
#define RED_LDS 4096                   // red[2][512]
#define LDS_TOT (W2_LDS + H1_LDS + RED_LDS)   // 102400 < 160 KiB

// async global->LDS, 16B/lane; LDS dest = wave-uniform base (+lane*16 by HW)
#define GLOAD_LDS16(g, l) __builtin_amdgcn_global_load_lds( \
    (const __attribute__((address_space(1))) void*)(g),     \
    (__attribute__((address_space(3))) void*)(l), 16, 0, 0)

// ---- prep: w2 fp32 -> bf16 in LDS-chunk order ----
// chunk c = kt*1024 + mt16*64 + ko*16 + row  ->  m = mt16*16+row, k = kt*32+ko*8+j
__global__ void w2_to_bf16(const float* __restrict__ w2, __bf16* __restrict__ w2b) {
    int i = blockIdx.x * 256 + threadIdx.x;   // 8*256*256 total
    int e = i >> 16, q = i & 65535, c = q >> 3, j = q & 7;
    int kt = c >> 10, mt16 = (c >> 6) & 15, ko = (c >> 4) & 3, row = c & 15;
    w2b[i] = (__bf16)w2[e * 65536 + (mt16 * 16 + row) * 256 + kt * 32 + ko * 8 + j];
}

__global__ __launch_bounds__(NT) void fused_mlp(
    const float* __restrict__ x,  const int* __restrict__ obj,
    const float* __restrict__ w1, const float* __restrict__ b1,
    const float* __restrict__ b2, const float* __restrict__ w3,
    const float* __restrict__ b3, const __bf16* __restrict__ w2b,
    float* __restrict__ out)
{
    extern __shared__ __align__(16) char smem[];
    char*  w2s = smem;                      // kt 0..1, chunk (kt*1024+mtile*64+koct*16+row)
    char*  h1t = smem + W2_LDS;             // [2 panels][kt*256 + nt*64 + lane]
    float* red = (float*)(smem + W2_LDS + H1_LDS);   // [2][512] ping-pong

    const int t    = threadIdx.x;
    const int lane = t & 63;
    const int wv   = t >> 6;                // wave owns rows [wv*32, wv*32+32)
    const int llo  = lane & 15;
    const int lhi  = lane >> 4;
    const int b    = blockIdx.x >> 4;       // sample (16 blocks each)
    const int g    = blockIdx.x & 15;
    const int e    = __builtin_amdgcn_readfirstlane(obj[b]);
    const __bf16* w2sw = w2b + (size_t)e * 65536;   // pre-swizzled chunk order

    // ---- stage kt 0..1 of W2[e] (32 KB): coalesced 1KB/wave loads ----
    #pragma unroll
    for (int it = 0; it < 4; ++it) {
        int c0 = it * NT + wv * 64;         // wave-uniform chunk base
        GLOAD_LDS16(w2sw + c0 * 8 + lane * 8, w2s + c0 * 16);
    }

    // ---- kt 2..7 A-frags in registers (48 VGPRs; cuts LDS A-traffic 6/8) ----
    bf16x8 aar[6][2];
    #pragma unroll
    for (int k2 = 0; k2 < 6; ++k2)
        #pragma unroll
        for (int mt = 0; mt < 2; ++mt) {
            int c = (2 + k2) * 1024 + (2 * wv + mt) * 64 + lane;
            aar[k2][mt] = *(const bf16x8*)(w2sw + c * 8);
        }

    // ---- L1 as MFMA: W1 A-frags + hoisted bias/weight frags, resident ----
    const float* w1e = w1 + e * 1536;
    bf16x8 aa1[2];
    f32x4  b1f[2], bv[2], wf[2];
    #pragma unroll
    for (int mt2 = 0; mt2 < 2; ++mt2) {
        const int m0 = (2 * wv + mt2) * 16;
        bf16x8 v = {};
        if (lhi == 0)
            #pragma unroll
            for (int j = 0; j < 6; ++j) v[j] = (__bf16)w1e[(m0 + llo) * 6 + j];
        aa1[mt2] = v;
        b1f[mt2] = *(const f32x4*)(b1 + e * 256 + m0 + lhi * 4);
        bv[mt2]  = *(const f32x4*)(b2 + e * 256 + m0 + lhi * 4);
        wf[mt2]  = *(const f32x4*)(w3 + e * 256 + m0 + lhi * 4);
    }
    const float b3e = b3[e];
    const float* xe = x + (size_t)b * 6 * V_TOTAL;

    bf16x8 xf[4];
    auto load_x = [&](int ic) {             // xf <- x(chunk ic), pre-cvt bf16
        #pragma unroll
        for (int pt = 0; pt < 4; ++pt) {
            bf16x8 v = {};
            #pragma unroll
            for (int i = 0; i < 6; ++i)
                v[i] = (__bf16)xe[i * V_TOTAL + (g * NV + ic) * 64 + pt * 16 + llo];
            xf[pt] = v;
        }
    };
    auto do_l1 = [&](int pan) {             // h1(panel) = relu(W1 x + b1), MFMA
        #pragma unroll
        for (int mt2 = 0; mt2 < 2; ++mt2) {
            const int o = (2 * wv + mt2) * 2 + (lhi >> 1);   // m-octet 0..31
            char* wbase = h1t + pan * 32768 + (o >> 2) * 4096 + (o & 3) * 256
                              + llo * 16 + (lhi & 1) * 8;
            #pragma unroll
            for (int pt = 0; pt < 4; ++pt) {
                f32x4 h = __builtin_amdgcn_mfma_f32_16x16x32_bf16(
                    aa1[mt2], xf[pt], b1f[mt2], 0, 0, 0);
                bf16x4 pk;
                #pragma unroll
                for (int r = 0; r < 4; ++r) pk[r] = (__bf16)fmaxf(h[r], 0.f);
                *(bf16x4*)(wbase + pt * 1024) = pk;
            }
        }
    };

    // ---- prologue: L1(0) into panel 0; prefetch x(1) ----
    load_x(0);
    do_l1(0);
    load_x(1);

    for (int iv = 0; iv < NV; ++iv) {
        __syncthreads();   // panel iv&1 ready; red[(iv-1)&1] ready; (iv==0: staging drained)

        if (iv > 0 && t < 64) {             // out-write for chunk iv-1
            const float* rq = red + ((iv - 1) & 1) * 512;
            float s = b3e;
            #pragma unroll
            for (int w8 = 0; w8 < 8; ++w8) s += rq[w8 * 64 + t];
            out[(size_t)b * V_TOTAL + (g * NV + iv - 1) * 64 + t] = s;
        }

        // ---- layer 2: kt 0..1 A from LDS, kt 2..7 A from registers ----
        f32x4 acc[2][4];
        #pragma unroll
        for (int mt = 0; mt < 2; ++mt)
            #pragma unroll
            for (int nt = 0; nt < 4; ++nt) acc[mt][nt] = bv[mt];
        const char* abase = w2s + wv * 2048 + lane * 16;
        const char* bbase = h1t + (iv & 1) * 32768 + lane * 16;
        __builtin_amdgcn_s_setprio(1);
        #pragma unroll
        for (int kt = 0; kt < 2; ++kt) {
            bf16x8 bb[4];
            #pragma unroll
            for (int nt = 0; nt < 4; ++nt)
                bb[nt] = *(const bf16x8*)(bbase + kt * 4096 + nt * 1024);
            #pragma unroll
            for (int mt = 0; mt < 2; ++mt) {
                const bf16x8 aw = *(const bf16x8*)(abase + kt * 16384 + mt * 1024);
                #pragma unroll
                for (int nt = 0; nt < 4; ++nt)
                    acc[mt][nt] = __builtin_amdgcn_mfma_f32_16x16x32_bf16(
                        aw, bb[nt], acc[mt][nt], 0, 0, 0);
            }
        }
        #pragma unroll
        for (int k2 = 0; k2 < 6; ++k2) {
            bf16x8 bb[4];
            #pragma unroll
            for (int nt = 0; nt < 4; ++nt)
                bb[nt] = *(const bf16x8*)(bbase + (2 + k2) * 4096 + nt * 1024);
            #pragma unroll
            for (int mt = 0; mt < 2; ++mt)
                #pragma unroll
                for (int nt = 0; nt < 4; ++nt)
                    acc[mt][nt] = __builtin_amdgcn_mfma_f32_16x16x32_bf16(
                        aar[k2][mt], bb[nt], acc[mt][nt], 0, 0, 0);
        }
        __builtin_amdgcn_s_setprio(0);

        // ---- layer 3 partials into red[iv&1] ----
        float p[4];
        #pragma unroll
        for (int nt = 0; nt < 4; ++nt) {
            float s = 0.f;
            #pragma unroll
            for (int mt = 0; mt < 2; ++mt)
                #pragma unroll
                for (int j = 0; j < 4; ++j)
                    s = fmaf(wf[mt][j], fmaxf(acc[mt][nt][j], 0.f), s);
            s += __shfl_xor(s, 16, 64);
            s += __shfl_xor(s, 32, 64);
            p[nt] = s;
        }
        float* rp = red + (iv & 1) * 512;
        if (lane < 16)
            #pragma unroll
            for (int nt = 0; nt < 4; ++nt)
                rp[wv * 64 + nt * 16 + lane] = p[nt];

        // ---- L1(iv+1) into panel (iv+1)&1 (overlaps other waves' L2) ----
        if (iv + 1 < NV) {
            do_l1((iv + 1) & 1);
            if (iv + 2 < NV) load_x(iv + 2);
        }
    }
    __syncthreads();   // red[(NV-1)&1] ready
    if (t < 64) {
        const float* rq = red + ((NV - 1) & 1) * 512;
        float s = b3e;
        #pragma unroll
        for (int w8 = 0; w8 < 8; ++w8) s += rq[w8 * 64 + t];
        out[(size_t)b * V_TOTAL + (g * NV + NV - 1) * 64 + t] = s;
    }
}

extern "C" void kernel_launch(void* const* d_in, const int* in_sizes, int n_in,
                              void* d_out, int out_size, void* d_ws, size_t ws_size,
                              hipStream_t stream) {
    const float* x   = (const float*)d_in[0];
    const int*   obj = (const int*)d_in[1];
    const float* w1  = (const float*)d_in[2];
    const float* b1  = (const float*)d_in[3];
    const float* w2  = (const float*)d_in[4];
    const float* b2  = (const float*)d_in[5];
    const float* w3  = (const float*)d_in[6];
    const float* b3  = (const float*)d_in[7];
    float*  out = (float*)d_out;
    __bf16* w2b = (__bf16*)d_ws;   // 8*256*256 bf16 = 1 MB, LDS-chunk order

    (void)hipFuncSetAttribute((const void*)fused_mlp,
                              hipFuncAttributeMaxDynamicSharedMemorySize, LDS_TOT);

    w2_to_bf16<<<2048, 256, 0, stream>>>(w2, w2b);
    fused_mlp<<<NBLK, NT, LDS_TOT, stream>>>(x, obj, w1, b1, b2, w3, b3, w2b, out);
}

// Round 25
// 79.465 us; speedup vs baseline: 1.3657x; 1.0244x over previous
//
#include <hip/hip_runtime.h>
#include <hip/hip_bf16.h>

typedef __bf16 bf16x8 __attribute__((ext_vector_type(8)));
typedef __bf16 bf16x4 __attribute__((ext_vector_type(4)));
typedef float  f32x4  __attribute__((ext_vector_type(4)));

#define V_TOTAL 32768
#define NT      512        // 8 waves; G0 = waves 0-3, G1 = waves 4-7 (1 of each per SIMD)
#define NV      32         // v-chunks of 64 positions per block
#define NBLK    256        // 1 block/CU; 16 blocks per sample

#define NKLDS   2                      // kt panels 0..1 in LDS; 2..7 in registers
#define W2_LDS  (NKLDS * 16384)        // 32768
#define H1_LDS  65536                  // h1[2] double buffer: 2 x 32 KB
#define RED_LDS 4096                   // red[2][512]
#define LDS_TOT (W2_LDS + H1_LDS + RED_LDS)   // 102400 < 160 KiB

// async global->LDS, 16B/lane; LDS dest = wave-uniform base (+lane*16 by HW)
#define GLOAD_LDS16(g, l) __builtin_amdgcn_global_load_lds( \
    (const __attribute__((address_space(1))) void*)(g),     \
    (__attribute__((address_space(3))) void*)(l), 16, 0, 0)

// ---- prep: w2 fp32 -> bf16 in LDS-chunk order ----
// chunk c = kt*1024 + mt16*64 + ko*16 + row  ->  m = mt16*16+row, k = kt*32+ko*8+j
__global__ void w2_to_bf16(const float* __restrict__ w2, __bf16* __restrict__ w2b) {
    int i = blockIdx.x * 256 + threadIdx.x;   // 8*256*256 total
    int e = i >> 16, q = i & 65535, c = q >> 3, j = q & 7;
    int kt = c >> 10, mt16 = (c >> 6) & 15, ko = (c >> 4) & 3, row = c & 15;
    w2b[i] = (__bf16)w2[e * 65536 + (mt16 * 16 + row) * 256 + kt * 32 + ko * 8 + j];
}

__global__ __launch_bounds__(NT) void fused_mlp(
    const float* __restrict__ x,  const int* __restrict__ obj,
    const float* __restrict__ w1, const float* __restrict__ b1,
    const float* __restrict__ b2, const float* __restrict__ w3,
    const float* __restrict__ b3, const __bf16* __restrict__ w2b,
    float* __restrict__ out)
{
    extern __shared__ __align__(16) char smem[];
    char*  w2s = smem;                      // kt 0..1, chunk (kt*1024+mtile*64+koct*16+row)
    char*  h1t = smem + W2_LDS;             // [2 panels][kt*256 + nt*64 + lane]
    float* red = (float*)(smem + W2_LDS + H1_LDS);   // [2][512] ping-pong

    const int t    = threadIdx.x;
    const int lane = t & 63;
    const int wv   = t >> 6;                // wave owns rows [wv*32, wv*32+32)
    const int llo  = lane & 15;
    const int lhi  = lane >> 4;
    const int b    = blockIdx.x >> 4;       // sample (16 blocks each)
    const int g    = blockIdx.x & 15;
    const int e    = __builtin_amdgcn_readfirstlane(obj[b]);
    const __bf16* w2sw = w2b + (size_t)e * 65536;   // pre-swizzled chunk order

    // ---- stage kt 0..1 of W2[e] (32 KB): coalesced 1KB/wave loads ----
    #pragma unroll
    for (int it = 0; it < 4; ++it) {
        int c0 = it * NT + wv * 64;         // wave-uniform chunk base
        GLOAD_LDS16(w2sw + c0 * 8 + lane * 8, w2s + c0 * 16);
    }

    // ---- kt 2..7 A-frags in registers (48 VGPRs) ----
    bf16x8 aar[6][2];
    #pragma unroll
    for (int k2 = 0; k2 < 6; ++k2)
        #pragma unroll
        for (int mt = 0; mt < 2; ++mt) {
            int c = (2 + k2) * 1024 + (2 * wv + mt) * 64 + lane;
            aar[k2][mt] = *(const bf16x8*)(w2sw + c * 8);
        }

    // ---- L1 as MFMA: W1 A-frags + hoisted bias/weight frags, resident ----
    const float* w1e = w1 + e * 1536;
    bf16x8 aa1[2];
    f32x4  b1f[2], bv[2], wf[2];
    #pragma unroll
    for (int mt2 = 0; mt2 < 2; ++mt2) {
        const int m0 = (2 * wv + mt2) * 16;
        bf16x8 v = {};
        if (lhi == 0)
            #pragma unroll
            for (int j = 0; j < 6; ++j) v[j] = (__bf16)w1e[(m0 + llo) * 6 + j];
        aa1[mt2] = v;
        b1f[mt2] = *(const f32x4*)(b1 + e * 256 + m0 + lhi * 4);
        bv[mt2]  = *(const f32x4*)(b2 + e * 256 + m0 + lhi * 4);
        wf[mt2]  = *(const f32x4*)(w3 + e * 256 + m0 + lhi * 4);
    }
    const float b3e = b3[e];
    const float* xe = x + (size_t)b * 6 * V_TOTAL;

    bf16x8 xf[4];
    auto load_x = [&](int ic) {             // xf <- x(chunk ic), pre-cvt bf16
        #pragma unroll
        for (int pt = 0; pt < 4; ++pt) {
            bf16x8 v = {};
            #pragma unroll
            for (int i = 0; i < 6; ++i)
                v[i] = (__bf16)xe[i * V_TOTAL + (g * NV + ic) * 64 + pt * 16 + llo];
            xf[pt] = v;
        }
    };
    auto do_l1 = [&](int pan) {             // group's 16-octet half of h1(panel)
        #pragma unroll
        for (int mt2 = 0; mt2 < 2; ++mt2) {
            const int o = (2 * wv + mt2) * 2 + (lhi >> 1);   // m-octet 0..31
            char* wbase = h1t + pan * 32768 + (o >> 2) * 4096 + (o & 3) * 256
                              + llo * 16 + (lhi & 1) * 8;
            #pragma unroll
            for (int pt = 0; pt < 4; ++pt) {
                f32x4 h = __builtin_amdgcn_mfma_f32_16x16x32_bf16(
                    aa1[mt2], xf[pt], b1f[mt2], 0, 0, 0);
                bf16x4 pk;
                #pragma unroll
                for (int r = 0; r < 4; ++r) pk[r] = (__bf16)fmaxf(h[r], 0.f);
                *(bf16x4*)(wbase + pt * 1024) = pk;
            }
        }
    };

    // ---- prologue: both groups build panel 0; prefetch x(1) ----
    load_x(0);
    do_l1(0);
    load_x(1);

    for (int iv = 0; iv < NV; ++iv) {
        __syncthreads();   // panel iv&1 complete; red[(iv-1)&1] ready

        if (iv > 0 && t < 64) {             // out-write for chunk iv-1
            const float* rq = red + ((iv - 1) & 1) * 512;
            float s = b3e;
            #pragma unroll
            for (int w8 = 0; w8 < 8; ++w8) s += rq[w8 * 64 + t];
            out[(size_t)b * V_TOTAL + (g * NV + iv - 1) * 64 + t] = s;
        }

        // ---- G1 (waves 4-7): VALU phase FIRST -> overlaps G0's MFMA phase ----
        if (wv >= 4 && iv + 1 < NV) {
            do_l1((iv + 1) & 1);
            if (iv + 2 < NV) load_x(iv + 2);
        }

        // ---- layer 2: kt 0..1 A from LDS, kt 2..7 A from registers ----
        f32x4 acc[2][4];
        #pragma unroll
        for (int mt = 0; mt < 2; ++mt)
            #pragma unroll
            for (int nt = 0; nt < 4; ++nt) acc[mt][nt] = bv[mt];
        const char* abase = w2s + wv * 2048 + lane * 16;
        const char* bbase = h1t + (iv & 1) * 32768 + lane * 16;
        __builtin_amdgcn_s_setprio(1);
        #pragma unroll
        for (int kt = 0; kt < 2; ++kt) {
            bf16x8 bb[4];
            #pragma unroll
            for (int nt = 0; nt < 4; ++nt)
                bb[nt] = *(const bf16x8*)(bbase + kt * 4096 + nt * 1024);
            #pragma unroll
            for (int mt = 0; mt < 2; ++mt) {
                const bf16x8 aw = *(const bf16x8*)(abase + kt * 16384 + mt * 1024);
                #pragma unroll
                for (int nt = 0; nt < 4; ++nt)
                    acc[mt][nt] = __builtin_amdgcn_mfma_f32_16x16x32_bf16(
                        aw, bb[nt], acc[mt][nt], 0, 0, 0);
            }
        }
        #pragma unroll
        for (int k2 = 0; k2 < 6; ++k2) {
            bf16x8 bb[4];
            #pragma unroll
            for (int nt = 0; nt < 4; ++nt)
                bb[nt] = *(const bf16x8*)(bbase + (2 + k2) * 4096 + nt * 1024);
            #pragma unroll
            for (int mt = 0; mt < 2; ++mt)
                #pragma unroll
                for (int nt = 0; nt < 4; ++nt)
                    acc[mt][nt] = __builtin_amdgcn_mfma_f32_16x16x32_bf16(
                        aar[k2][mt], bb[nt], acc[mt][nt], 0, 0, 0);
        }
        __builtin_amdgcn_s_setprio(0);

        // ---- layer 3 partials into red[iv&1] ----
        float p[4];
        #pragma unroll
        for (int nt = 0; nt < 4; ++nt) {
            float s = 0.f;
            #pragma unroll
            for (int mt = 0; mt < 2; ++mt)
                #pragma unroll
                for (int j = 0; j < 4; ++j)
                    s = fmaf(wf[mt][j], fmaxf(acc[mt][nt][j], 0.f), s);
            s += __shfl_xor(s, 16, 64);
            s += __shfl_xor(s, 32, 64);
            p[nt] = s;
        }
        float* rp = red + (iv & 1) * 512;
        if (lane < 16)
            #pragma unroll
            for (int nt = 0; nt < 4; ++nt)
                rp[wv * 64 + nt * 16 + lane] = p[nt];

        // ---- G0 (waves 0-3): VALU phase LAST -> overlaps G1's MFMA phase ----
        if (wv < 4 && iv + 1 < NV) {
            do_l1((iv + 1) & 1);
            if (iv + 2 < NV) load_x(iv + 2);
        }
    }
    __syncthreads();   // red[(NV-1)&1] ready
    if (t < 64) {
        const float* rq = red + ((NV - 1) & 1) * 512;
        float s = b3e;
        #pragma unroll
        for (int w8 = 0; w8 < 8; ++w8) s += rq[w8 * 64 + t];
        out[(size_t)b * V_TOTAL + (g * NV + NV - 1) * 64 + t] = s;
    }
}

extern "C" void kernel_launch(void* const* d_in, const int* in_sizes, int n_in,
                              void* d_out, int out_size, void* d_ws, size_t ws_size,
                              hipStream_t stream) {
    const float* x   = (const float*)d_in[0];
    const int*   obj = (const int*)d_in[1];
    const float* w1  = (const float*)d_in[2];
    const float* b1  = (const float*)d_in[3];
    const float* w2  = (const float*)d_in[4];
    const float* b2  = (const float*)d_in[5];
    const float* w3  = (const float*)d_in[6];
    const float* b3  = (const float*)d_in[7];
    float*  out = (float*)d_out;
    __bf16* w2b = (__bf16*)d_ws;   // 8*256*256 bf16 = 1 MB, LDS-chunk order

    (void)hipFuncSetAttribute((const void*)fused_mlp,
                              hipFuncAttributeMaxDynamicSharedMemorySize, LDS_TOT);

    w2_to_bf16<<<2048, 256, 0, stream>>>(w2, w2b);
    fused_mlp<<<NBLK, NT, LDS_TOT, stream>>>(x, obj, w1, b1, b2, w3, b3, w2b, out);
}

// Round 26
// 79.243 us; speedup vs baseline: 1.3695x; 1.0028x over previous
//
#include <hip/hip_runtime.h>
#include <hip/hip_bf16.h>

typedef __bf16 bf16x8 __attribute__((ext_vector_type(8)));
typedef __bf16 bf16x4 __attribute__((ext_vector_type(4)));
typedef float  f32x4  __attribute__((ext_vector_type(4)));

#define V_TOTAL 32768
#define NT      512        // 8 waves; G0 = waves 0-3, G1 = waves 4-7 (1 of each per SIMD)
#define NV      32         // v-chunks of 64 positions per block
#define NBLK    256        // 1 block/CU; 16 blocks per sample

#define NKLDS   2                      // kt panels 0..1 in LDS; 2..7 in registers
#define W2_LDS  (NKLDS * 16384)        // 32768
#define H1_LDS  65536                  // h1[2] double buffer: 2 x 32 KB
#define RED_LDS 4096                   // red[2][512]
#define LDS_TOT (W2_LDS + H1_LDS + RED_LDS)   // 102400 < 160 KiB

// async global->LDS, 16B/lane; LDS dest = wave-uniform base (+lane*16 by HW)
#define GLOAD_LDS16(g, l) __builtin_amdgcn_global_load_lds( \
    (const __attribute__((address_space(1))) void*)(g),     \
    (__attribute__((address_space(3))) void*)(l), 16, 0, 0)

// ---- prep: w2 fp32 -> bf16 in LDS-chunk order ----
// chunk c = kt*1024 + mt16*64 + ko*16 + row  ->  m = mt16*16+row, k = kt*32+ko*8+j
__global__ void w2_to_bf16(const float* __restrict__ w2, __bf16* __restrict__ w2b) {
    int i = blockIdx.x * 256 + threadIdx.x;   // 8*256*256 total
    int e = i >> 16, q = i & 65535, c = q >> 3, j = q & 7;
    int kt = c >> 10, mt16 = (c >> 6) & 15, ko = (c >> 4) & 3, row = c & 15;
    w2b[i] = (__bf16)w2[e * 65536 + (mt16 * 16 + row) * 256 + kt * 32 + ko * 8 + j];
}

__global__ __launch_bounds__(NT) void fused_mlp(
    const float* __restrict__ x,  const int* __restrict__ obj,
    const float* __restrict__ w1, const float* __restrict__ b1,
    const float* __restrict__ b2, const float* __restrict__ w3,
    const float* __restrict__ b3, const __bf16* __restrict__ w2b,
    float* __restrict__ out)
{
    extern __shared__ __align__(16) char smem[];
    char*  w2s = smem;                      // kt 0..1, chunk (kt*1024+mtile*64+koct*16+row)
    char*  h1t = smem + W2_LDS;             // [2 panels][kt*256 + nt*64 + lane]
    float* red = (float*)(smem + W2_LDS + H1_LDS);   // [2][512] ping-pong

    const int t    = threadIdx.x;
    const int lane = t & 63;
    const int wv   = t >> 6;                // wave owns rows [wv*32, wv*32+32)
    const int llo  = lane & 15;
    const int lhi  = lane >> 4;
    const int b    = blockIdx.x >> 4;       // sample (16 blocks each)
    const int g    = blockIdx.x & 15;
    const int e    = __builtin_amdgcn_readfirstlane(obj[b]);
    const __bf16* w2sw = w2b + (size_t)e * 65536;   // pre-swizzled chunk order

    // ---- stage kt 0..1 of W2[e] (32 KB): coalesced 1KB/wave loads ----
    #pragma unroll
    for (int it = 0; it < 4; ++it) {
        int c0 = it * NT + wv * 64;         // wave-uniform chunk base
        GLOAD_LDS16(w2sw + c0 * 8 + lane * 8, w2s + c0 * 16);
    }

    // ---- kt 2..7 A-frags in registers (48 VGPRs) ----
    bf16x8 aar[6][2];
    #pragma unroll
    for (int k2 = 0; k2 < 6; ++k2)
        #pragma unroll
        for (int mt = 0; mt < 2; ++mt) {
            int c = (2 + k2) * 1024 + (2 * wv + mt) * 64 + lane;
            aar[k2][mt] = *(const bf16x8*)(w2sw + c * 8);
        }

    // ---- L1 as MFMA: W1 A-frags + hoisted bias/weight frags, resident ----
    const float* w1e = w1 + e * 1536;
    bf16x8 aa1[2];
    f32x4  b1f[2], bv[2], wf[2];
    #pragma unroll
    for (int mt2 = 0; mt2 < 2; ++mt2) {
        const int m0 = (2 * wv + mt2) * 16;
        bf16x8 v = {};
        if (lhi == 0)
            #pragma unroll
            for (int j = 0; j < 6; ++j) v[j] = (__bf16)w1e[(m0 + llo) * 6 + j];
        aa1[mt2] = v;
        b1f[mt2] = *(const f32x4*)(b1 + e * 256 + m0 + lhi * 4);
        bv[mt2]  = *(const f32x4*)(b2 + e * 256 + m0 + lhi * 4);
        wf[mt2]  = *(const f32x4*)(w3 + e * 256 + m0 + lhi * 4);
    }
    const float b3e = b3[e];
    const float* xe = x + (size_t)b * 6 * V_TOTAL;

    bf16x8 xf[4];
    auto load_x = [&](int ic) {             // xf <- x(chunk ic), pre-cvt bf16
        #pragma unroll
        for (int pt = 0; pt < 4; ++pt) {
            bf16x8 v = {};
            #pragma unroll
            for (int i = 0; i < 6; ++i)
                v[i] = (__bf16)xe[i * V_TOTAL + (g * NV + ic) * 64 + pt * 16 + llo];
            xf[pt] = v;
        }
    };
    auto do_l1 = [&](int pan) {             // group's 16-octet half of h1(panel)
        #pragma unroll
        for (int mt2 = 0; mt2 < 2; ++mt2) {
            const int o = (2 * wv + mt2) * 2 + (lhi >> 1);   // m-octet 0..31
            char* wbase = h1t + pan * 32768 + (o >> 2) * 4096 + (o & 3) * 256
                              + llo * 16 + (lhi & 1) * 8;
            #pragma unroll
            for (int pt = 0; pt < 4; ++pt) {
                f32x4 h = __builtin_amdgcn_mfma_f32_16x16x32_bf16(
                    aa1[mt2], xf[pt], b1f[mt2], 0, 0, 0);
                bf16x4 pk;
                #pragma unroll
                for (int r = 0; r < 4; ++r) pk[r] = (__bf16)fmaxf(h[r], 0.f);
                *(bf16x4*)(wbase + pt * 1024) = pk;
            }
        }
    };

    // ---- prologue: both groups build panel 0; prefetch x(1) ----
    load_x(0);
    do_l1(0);
    load_x(1);

    for (int iv = 0; iv < NV; ++iv) {
        __syncthreads();   // panel iv&1 complete; red[(iv-1)&1] ready

        if (iv > 0 && t < 64) {             // out-write for chunk iv-1
            const float* rq = red + ((iv - 1) & 1) * 512;
            float s = b3e;
            #pragma unroll
            for (int w8 = 0; w8 < 8; ++w8) s += rq[w8 * 64 + t];
            out[(size_t)b * V_TOTAL + (g * NV + iv - 1) * 64 + t] = s;
        }

        // ---- G1 (waves 4-7): VALU phase FIRST -> overlaps G0's MFMA phase ----
        if (wv >= 4 && iv + 1 < NV) {
            do_l1((iv + 1) & 1);
            if (iv + 2 < NV) load_x(iv + 2);
        }

        // ---- layer 2: kt 0..1 A from LDS, kt 2..7 A from registers ----
        // NO s_setprio here: with staggered phases, prio-1 on the MFMA wave
        // STARVES its SIMD-mate's VALU phase (T5 failure mode) — the overlap
        // needs equal priority so the scheduler co-issues both pipes (m114).
        f32x4 acc[2][4];
        #pragma unroll
        for (int mt = 0; mt < 2; ++mt)
            #pragma unroll
            for (int nt = 0; nt < 4; ++nt) acc[mt][nt] = bv[mt];
        const char* abase = w2s + wv * 2048 + lane * 16;
        const char* bbase = h1t + (iv & 1) * 32768 + lane * 16;
        #pragma unroll
        for (int kt = 0; kt < 2; ++kt) {
            bf16x8 bb[4];
            #pragma unroll
            for (int nt = 0; nt < 4; ++nt)
                bb[nt] = *(const bf16x8*)(bbase + kt * 4096 + nt * 1024);
            #pragma unroll
            for (int mt = 0; mt < 2; ++mt) {
                const bf16x8 aw = *(const bf16x8*)(abase + kt * 16384 + mt * 1024);
                #pragma unroll
                for (int nt = 0; nt < 4; ++nt)
                    acc[mt][nt] = __builtin_amdgcn_mfma_f32_16x16x32_bf16(
                        aw, bb[nt], acc[mt][nt], 0, 0, 0);
            }
        }
        #pragma unroll
        for (int k2 = 0; k2 < 6; ++k2) {
            bf16x8 bb[4];
            #pragma unroll
            for (int nt = 0; nt < 4; ++nt)
                bb[nt] = *(const bf16x8*)(bbase + (2 + k2) * 4096 + nt * 1024);
            #pragma unroll
            for (int mt = 0; mt < 2; ++mt)
                #pragma unroll
                for (int nt = 0; nt < 4; ++nt)
                    acc[mt][nt] = __builtin_amdgcn_mfma_f32_16x16x32_bf16(
                        aar[k2][mt], bb[nt], acc[mt][nt], 0, 0, 0);
        }

        // ---- layer 3 partials into red[iv&1] ----
        float p[4];
        #pragma unroll
        for (int nt = 0; nt < 4; ++nt) {
            float s = 0.f;
            #pragma unroll
            for (int mt = 0; mt < 2; ++mt)
                #pragma unroll
                for (int j = 0; j < 4; ++j)
                    s = fmaf(wf[mt][j], fmaxf(acc[mt][nt][j], 0.f), s);
            s += __shfl_xor(s, 16, 64);
            s += __shfl_xor(s, 32, 64);
            p[nt] = s;
        }
        float* rp = red + (iv & 1) * 512;
        if (lane < 16)
            #pragma unroll
            for (int nt = 0; nt < 4; ++nt)
                rp[wv * 64 + nt * 16 + lane] = p[nt];

        // ---- G0 (waves 0-3): VALU phase LAST -> overlaps G1's MFMA phase ----
        if (wv < 4 && iv + 1 < NV) {
            do_l1((iv + 1) & 1);
            if (iv + 2 < NV) load_x(iv + 2);
        }
    }
    __syncthreads();   // red[(NV-1)&1] ready
    if (t < 64) {
        const float* rq = red + ((NV - 1) & 1) * 512;
        float s = b3e;
        #pragma unroll
        for (int w8 = 0; w8 < 8; ++w8) s += rq[w8 * 64 + t];
        out[(size_t)b * V_TOTAL + (g * NV + NV - 1) * 64 + t] = s;
    }
}

extern "C" void kernel_launch(void* const* d_in, const int* in_sizes, int n_in,
                              void* d_out, int out_size, void* d_ws, size_t ws_size,
                              hipStream_t stream) {
    const float* x   = (const float*)d_in[0];
    const int*   obj = (const int*)d_in[1];
    const float* w1  = (const float*)d_in[2];
    const float* b1  = (const float*)d_in[3];
    const float* w2  = (const float*)d_in[4];
    const float* b2  = (const float*)d_in[5];
    const float* w3  = (const float*)d_in[6];
    const float* b3  = (const float*)d_in[7];
    float*  out = (float*)d_out;
    __bf16* w2b = (__bf16*)d_ws;   // 8*256*256 bf16 = 1 MB, LDS-chunk order

    (void)hipFuncSetAttribute((const void*)fused_mlp,
                              hipFuncAttributeMaxDynamicSharedMemorySize, LDS_TOT);

    w2_to_bf16<<<2048, 256, 0, stream>>>(w2, w2b);
    fused_mlp<<<NBLK, NT, LDS_TOT, stream>>>(x, obj, w1, b1, b2, w3, b3, w2b, out);
}